// Round 2
// baseline (404.265 us; speedup 1.0000x reference)
//
#include <hip/hip_runtime.h>
#include <hip/hip_bf16.h>

// QLoRA SwiGLU MLP, B=16 tokens, d=4096, h=11008, r=2.
// tile(wq,(1,4)) => x @ W^T == fold4(x) @ wq^T  (skinny GEMM, K = in/4).
// Folded activations staged in LDS as bf16 (halves LDS, 32KB / 88KB).
// LoRA r=2 fused into epilogues.

#define NB     16
#define DMODEL 4096
#define HID    11008
#define DQ     1024   // DMODEL/4
#define HQ     2752   // HID/4

// workspace layout (float offsets)
#define XS1B_OFF 0        // xs bf16 [16][1024] = 8192 floats
#define T1_OFF   8192     // [16][2] f32
#define T3_OFF   8224
#define HVT_OFF  8256     // hvecT f32 [11008][16]
#define HSB_OFF  184384   // hs bf16 [16][2752] = 22016 floats
#define T2_OFF   206400   // [16][2] f32

__device__ __forceinline__ unsigned short f2bf(float f) {
  unsigned u = __float_as_uint(f);
  unsigned r = u + 0x7fffu + ((u >> 16) & 1u);   // RNE
  return (unsigned short)(r >> 16);
}
__device__ __forceinline__ unsigned pack2(float lo, float hi) {
  return (unsigned)f2bf(lo) | ((unsigned)f2bf(hi) << 16);
}

// ---------------------------------------------------------------------------
// prep1: xs[b][j] = sum_k x[b][k*1024+j] (stored bf16); t1,t3 = LoRA A dots.
__global__ __launch_bounds__(256) void k_prep1(const float* __restrict__ x,
                                               const float* __restrict__ a1,
                                               const float* __restrict__ a3,
                                               float* __restrict__ ws) {
  const int b = blockIdx.x, t = threadIdx.x;
  const float4* x4  = (const float4*)(x) + b * (DMODEL / 4);
  const float4* a14 = (const float4*)a1;
  const float4* a34 = (const float4*)a3;
  float4 xs = make_float4(0.f, 0.f, 0.f, 0.f);
  float s10 = 0.f, s11 = 0.f, s30 = 0.f, s31 = 0.f;
#pragma unroll
  for (int k = 0; k < 4; ++k) {
    float4 xv  = x4[k * 256 + t];
    xs.x += xv.x; xs.y += xv.y; xs.z += xv.z; xs.w += xv.w;
    float4 a10 = a14[k * 256 + t];
    float4 a11 = a14[1024 + k * 256 + t];
    float4 a30 = a34[k * 256 + t];
    float4 a31 = a34[1024 + k * 256 + t];
    s10 += xv.x * a10.x + xv.y * a10.y + xv.z * a10.z + xv.w * a10.w;
    s11 += xv.x * a11.x + xv.y * a11.y + xv.z * a11.z + xv.w * a11.w;
    s30 += xv.x * a30.x + xv.y * a30.y + xv.z * a30.z + xv.w * a30.w;
    s31 += xv.x * a31.x + xv.y * a31.y + xv.z * a31.z + xv.w * a31.w;
  }
  ((uint2*)(ws + XS1B_OFF))[b * 256 + t] =
      make_uint2(pack2(xs.x, xs.y), pack2(xs.z, xs.w));

  __shared__ float4 rb[256];
  rb[t] = make_float4(s10, s11, s30, s31);
  __syncthreads();
  for (int s = 128; s > 0; s >>= 1) {
    if (t < s) {
      rb[t].x += rb[t + s].x; rb[t].y += rb[t + s].y;
      rb[t].z += rb[t + s].z; rb[t].w += rb[t + s].w;
    }
    __syncthreads();
  }
  if (t == 0) {
    ws[T1_OFF + b * 2]     = rb[0].x;
    ws[T1_OFF + b * 2 + 1] = rb[0].y;
    ws[T3_OFF + b * 2]     = rb[0].z;
    ws[T3_OFF + b * 2 + 1] = rb[0].w;
  }
}

// ---------------------------------------------------------------------------
// gateup: 501 blocks x 512 thr; 22 cols/block; wave does 3 col-tasks with
// double-buffered weight regs. xs bf16 in 32KB LDS. Halving-butterfly reduce.
#define GU_LOADW(OCOL, W1, W3) do {                                         \
    const float4* _p1 = (const float4*)w1q + (size_t)(OCOL) * 256;          \
    const float4* _p3 = (const float4*)w3q + (size_t)(OCOL) * 256;          \
    _Pragma("unroll")                                                       \
    for (int c = 0; c < 4; ++c) {                                           \
      W1[c] = _p1[c * 64 + lane];                                           \
      W3[c] = _p3[c * 64 + lane];                                           \
    }                                                                       \
  } while (0)

#define GU_COMPUTE(OCOL, W1, W3) do {                                       \
    float V[32];                                                            \
    _Pragma("unroll") for (int i = 0; i < 32; ++i) V[i] = 0.f;              \
    _Pragma("unroll")                                                       \
    for (int c = 0; c < 4; ++c) {                                           \
      const int idx = c * 64 + lane;                                        \
      const float4 w1v = W1[c], w3v = W3[c];                                \
      _Pragma("unroll")                                                     \
      for (int b = 0; b < 16; ++b) {                                        \
        uint2 p = ldsb[b * 256 + idx];                                      \
        float x0 = __uint_as_float(p.x << 16);                              \
        float x1 = __uint_as_float(p.x & 0xffff0000u);                      \
        float x2 = __uint_as_float(p.y << 16);                              \
        float x3 = __uint_as_float(p.y & 0xffff0000u);                      \
        V[2 * b]     += w1v.x * x0 + w1v.y * x1 + w1v.z * x2 + w1v.w * x3;  \
        V[2 * b + 1] += w3v.x * x0 + w3v.y * x1 + w3v.z * x2 + w3v.w * x3;  \
      }                                                                     \
    }                                                                       \
    _Pragma("unroll")                                                       \
    for (int s = 0; s < 4; ++s) {                                           \
      const int off = 1 << s, n2 = 16 >> s;                                 \
      _Pragma("unroll")                                                     \
      for (int i = 0; i < n2; ++i) {                                        \
        float lo = V[i], hi = V[i + n2];                                    \
        float send = (lane & off) ? lo : hi;                                \
        float got = __shfl_xor(send, off);                                  \
        V[i] = (lane & off) ? (hi + got) : (lo + got);                      \
      }                                                                     \
    }                                                                       \
    V[0] += __shfl_xor(V[0], 16); V[0] += __shfl_xor(V[0], 32);             \
    V[1] += __shfl_xor(V[1], 16); V[1] += __shfl_xor(V[1], 32);             \
    if (lane < 16) {                                                        \
      const int b = ((lane & 1) << 3) | ((lane & 2) << 1) |                 \
                    ((lane & 4) >> 1) | ((lane & 8) >> 3);                  \
      const float g = V[0] + 0.5f * (ws[T1_OFF + 2 * b] * b1[2 * (OCOL)] +  \
                                     ws[T1_OFF + 2 * b + 1] * b1[2 * (OCOL) + 1]); \
      const float u = V[1] + 0.5f * (ws[T3_OFF + 2 * b] * b3[2 * (OCOL)] +  \
                                     ws[T3_OFF + 2 * b + 1] * b3[2 * (OCOL) + 1]); \
      hvecT[(OCOL) * 16 + b] = (g / (1.f + __expf(-g))) * u;                \
    }                                                                       \
  } while (0)

__global__ __launch_bounds__(512, 4) void k_gateup(const float* __restrict__ w1q,
                                                   const float* __restrict__ w3q,
                                                   const float* __restrict__ b1,
                                                   const float* __restrict__ b3,
                                                   const float* __restrict__ ws,
                                                   float* __restrict__ hvecT) {
  __shared__ uint4 lds4[2048];   // xs bf16 [16][1024] = 32 KB
  const int t = threadIdx.x;
  const uint4* xsb4 = (const uint4*)(ws + XS1B_OFF);
#pragma unroll
  for (int i = 0; i < 4; ++i) lds4[t + i * 512] = xsb4[t + i * 512];
  __syncthreads();

  const int wave = t >> 6, lane = t & 63;
  const uint2* ldsb = (const uint2*)lds4;     // [b*256 + idx], 4 bf16 each
  const int obase = blockIdx.x * 22;

  const int o0 = obase + wave;
  const int o1 = obase + 8 + wave;
  const int o2 = obase + 16 + wave;
  const bool v0 = (o0 < HID);
  const bool v1 = (o1 < HID);
  const bool v2 = (wave < 6) && (o2 < HID);
  const int l0 = v0 ? o0 : 0, l1 = v1 ? o1 : 0, l2 = v2 ? o2 : 0;

  float4 A1[4], A3[4], B1[4], B3[4];
  GU_LOADW(l0, A1, A3);
  GU_LOADW(l1, B1, B3);
  if (v0) GU_COMPUTE(o0, A1, A3);
  GU_LOADW(l2, A1, A3);
  if (v1) GU_COMPUTE(o1, B1, B3);
  if (v2) GU_COMPUTE(o2, A1, A3);
}

// ---------------------------------------------------------------------------
// prep2: hs[b][j] = sum_k hvec[b][k*2752+j] (stored bf16); t2 = hvec·a2^T.
__global__ __launch_bounds__(256) void k_prep2(const float* __restrict__ hvecT,
                                               const float* __restrict__ a2,
                                               float* __restrict__ ws) {
  const int b = blockIdx.x, t = threadIdx.x;
  float s0 = 0.f, s1 = 0.f;
  unsigned short* hsb = (unsigned short*)(ws + HSB_OFF);
  for (int j = t; j < HQ; j += 256) {
    float v0 = hvecT[j * 16 + b];
    float v1 = hvecT[(j + HQ) * 16 + b];
    float v2 = hvecT[(j + 2 * HQ) * 16 + b];
    float v3 = hvecT[(j + 3 * HQ) * 16 + b];
    hsb[b * HQ + j] = f2bf(v0 + v1 + v2 + v3);
    s0 += v0 * a2[j] + v1 * a2[j + HQ] + v2 * a2[j + 2 * HQ] + v3 * a2[j + 3 * HQ];
    s1 += v0 * a2[HID + j] + v1 * a2[HID + j + HQ] +
          v2 * a2[HID + j + 2 * HQ] + v3 * a2[HID + j + 3 * HQ];
  }
  __shared__ float2 rb[256];
  rb[t] = make_float2(s0, s1);
  __syncthreads();
  for (int s = 128; s > 0; s >>= 1) {
    if (t < s) { rb[t].x += rb[t + s].x; rb[t].y += rb[t + s].y; }
    __syncthreads();
  }
  if (t == 0) { ws[T2_OFF + b * 2] = rb[0].x; ws[T2_OFF + b * 2 + 1] = rb[0].y; }
}

// ---------------------------------------------------------------------------
// down: 256 blocks x 1024 thr, 1 col/wave, hs bf16 fully LDS-resident (88 KB),
// single stage, full-K loop, halving reduce.
__global__ __launch_bounds__(1024, 4) void k_down(const float* __restrict__ w2q,
                                                  const float* __restrict__ b2,
                                                  const float* __restrict__ ws,
                                                  float* __restrict__ out) {
  __shared__ uint4 lds4[5504];   // hs bf16 [16][2752] = 88 KB
  const int t = threadIdx.x;
  const uint4* hsb4 = (const uint4*)(ws + HSB_OFF);
  for (int i = t; i < 5504; i += 1024) lds4[i] = hsb4[i];
  __syncthreads();

  const int wave = t >> 6, lane = t & 63;
  const uint2* ldsb = (const uint2*)lds4;     // [b*688 + j], 4 bf16 each
  const int o = blockIdx.x * 16 + wave;
  const float4* wp = (const float4*)w2q + (size_t)o * 688;

  float V[16];
#pragma unroll
  for (int i = 0; i < 16; ++i) V[i] = 0.f;

#pragma unroll
  for (int cc = 0; cc < 10; ++cc) {
    const int j = cc * 64 + lane;
    const float4 wv = wp[j];
#pragma unroll
    for (int b = 0; b < 16; ++b) {
      uint2 p = ldsb[b * 688 + j];
      float x0 = __uint_as_float(p.x << 16);
      float x1 = __uint_as_float(p.x & 0xffff0000u);
      float x2 = __uint_as_float(p.y << 16);
      float x3 = __uint_as_float(p.y & 0xffff0000u);
      V[b] += wv.x * x0 + wv.y * x1 + wv.z * x2 + wv.w * x3;
    }
  }
  if (lane < 48) {                      // tail: j = 640..687
    const int j = 640 + lane;
    const float4 wv = wp[j];
#pragma unroll
    for (int b = 0; b < 16; ++b) {
      uint2 p = ldsb[b * 688 + j];
      float x0 = __uint_as_float(p.x << 16);
      float x1 = __uint_as_float(p.x & 0xffff0000u);
      float x2 = __uint_as_float(p.y << 16);
      float x3 = __uint_as_float(p.y & 0xffff0000u);
      V[b] += wv.x * x0 + wv.y * x1 + wv.z * x2 + wv.w * x3;
    }
  }

#pragma unroll
  for (int s = 0; s < 4; ++s) {
    const int off = 1 << s, n2 = 8 >> s;
#pragma unroll
    for (int i = 0; i < n2; ++i) {
      float lo = V[i], hi = V[i + n2];
      float send = (lane & off) ? lo : hi;
      float got = __shfl_xor(send, off);
      V[i] = (lane & off) ? (hi + got) : (lo + got);
    }
  }
  V[0] += __shfl_xor(V[0], 16);
  V[0] += __shfl_xor(V[0], 32);

  if (lane < 16) {
    const int b = ((lane & 1) << 3) | ((lane & 2) << 1) |
                  ((lane & 4) >> 1) | ((lane & 8) >> 3);
    out[b * DMODEL + o] = V[0] + 0.5f * (ws[T2_OFF + 2 * b] * b2[2 * o] +
                                         ws[T2_OFF + 2 * b + 1] * b2[2 * o + 1]);
  }
}

// ---------------------------------------------------------------------------
extern "C" void kernel_launch(void* const* d_in, const int* in_sizes, int n_in,
                              void* d_out, int out_size, void* d_ws, size_t ws_size,
                              hipStream_t stream) {
  const float* x   = (const float*)d_in[0];
  const float* w1q = (const float*)d_in[1];
  const float* a1  = (const float*)d_in[2];
  const float* b1  = (const float*)d_in[3];
  const float* w3q = (const float*)d_in[4];
  const float* a3  = (const float*)d_in[5];
  const float* b3  = (const float*)d_in[6];
  const float* w2q = (const float*)d_in[7];
  const float* a2  = (const float*)d_in[8];
  const float* b2  = (const float*)d_in[9];
  float* out = (float*)d_out;
  float* ws  = (float*)d_ws;
  float* hvecT = ws + HVT_OFF;

  k_prep1<<<16, 256, 0, stream>>>(x, a1, a3, ws);
  k_gateup<<<501, 512, 0, stream>>>(w1q, w3q, b1, b3, ws, hvecT);
  k_prep2<<<16, 256, 0, stream>>>(hvecT, a2, ws);
  k_down<<<256, 1024, 0, stream>>>(w2q, b2, ws, out);
}

// Round 4
// 198.378 us; speedup vs baseline: 2.0379x; 2.0379x over previous
//
#include <hip/hip_runtime.h>
#include <hip/hip_bf16.h>

// QLoRA SwiGLU MLP, B=16 tokens, d=4096, h=11008, r=2.
// tile(wq,(1,4)) => x @ W^T == fold4(x) @ wq^T  (skinny GEMM, K = in/4).
// gateup: xs f32 in 64KB LDS, 2 cols/wave pipelined (16 loads in flight).
// down:   hs bf16 in 88KB LDS, 16 waves, 1 col/wave.
// LoRA r=2 fused into epilogues. NO min-waves launch bounds (R2 spill lesson).
// R3 bug fixed: T2_OFF must be HSB_OFF + 22016 (hs = 16*2752 bf16 = 22016 f32),
// not +11008 — the overlap let t2 writes clobber hs token 8.

#define NB     16
#define DMODEL 4096
#define HID    11008
#define DQ     1024   // DMODEL/4
#define HQ     2752   // HID/4

// workspace layout (float offsets)
#define XS1_OFF 0         // xs f32 [16][1024]
#define T1_OFF  16384     // [16][2] f32
#define T3_OFF  16416
#define HVT_OFF 16448     // hvecT f32 [11008][16]
#define HSB_OFF 192576    // hs bf16 [16][2752] = 22016 floats
#define T2_OFF  214592    // [16][2] f32

__device__ __forceinline__ unsigned short f2bf(float f) {
  unsigned u = __float_as_uint(f);
  unsigned r = u + 0x7fffu + ((u >> 16) & 1u);   // RNE
  return (unsigned short)(r >> 16);
}

// ---------------------------------------------------------------------------
// prep1: xs[b][j] = sum_k x[b][k*1024+j] (f32); t1,t3 = LoRA A dots.
__global__ __launch_bounds__(256) void k_prep1(const float* __restrict__ x,
                                               const float* __restrict__ a1,
                                               const float* __restrict__ a3,
                                               float* __restrict__ ws) {
  const int b = blockIdx.x, t = threadIdx.x;
  const float4* x4  = (const float4*)(x) + b * (DMODEL / 4);
  const float4* a14 = (const float4*)a1;
  const float4* a34 = (const float4*)a3;
  float4 xs = make_float4(0.f, 0.f, 0.f, 0.f);
  float s10 = 0.f, s11 = 0.f, s30 = 0.f, s31 = 0.f;
#pragma unroll
  for (int k = 0; k < 4; ++k) {
    float4 xv  = x4[k * 256 + t];
    xs.x += xv.x; xs.y += xv.y; xs.z += xv.z; xs.w += xv.w;
    float4 a10 = a14[k * 256 + t];
    float4 a11 = a14[1024 + k * 256 + t];
    float4 a30 = a34[k * 256 + t];
    float4 a31 = a34[1024 + k * 256 + t];
    s10 += xv.x * a10.x + xv.y * a10.y + xv.z * a10.z + xv.w * a10.w;
    s11 += xv.x * a11.x + xv.y * a11.y + xv.z * a11.z + xv.w * a11.w;
    s30 += xv.x * a30.x + xv.y * a30.y + xv.z * a30.z + xv.w * a30.w;
    s31 += xv.x * a31.x + xv.y * a31.y + xv.z * a31.z + xv.w * a31.w;
  }
  ((float4*)(ws + XS1_OFF))[b * 256 + t] = xs;

  __shared__ float4 rb[256];
  rb[t] = make_float4(s10, s11, s30, s31);
  __syncthreads();
  for (int s = 128; s > 0; s >>= 1) {
    if (t < s) {
      rb[t].x += rb[t + s].x; rb[t].y += rb[t + s].y;
      rb[t].z += rb[t + s].z; rb[t].w += rb[t + s].w;
    }
    __syncthreads();
  }
  if (t == 0) {
    ws[T1_OFF + b * 2]     = rb[0].x;
    ws[T1_OFF + b * 2 + 1] = rb[0].y;
    ws[T3_OFF + b * 2]     = rb[0].z;
    ws[T3_OFF + b * 2 + 1] = rb[0].w;
  }
}

// ---------------------------------------------------------------------------
// gateup: 688 blocks x 512 thr; 16 cols/block; 2 cols/wave, both cols' weight
// loads issued before first compute (counted-vmcnt overlap). xs f32 64KB LDS.
#define GU_LOADW(OCOL, W1, W3) do {                                         \
    const float4* _p1 = (const float4*)w1q + (size_t)(OCOL) * 256;          \
    const float4* _p3 = (const float4*)w3q + (size_t)(OCOL) * 256;          \
    _Pragma("unroll")                                                       \
    for (int c = 0; c < 4; ++c) {                                           \
      W1[c] = _p1[c * 64 + lane];                                           \
      W3[c] = _p3[c * 64 + lane];                                           \
    }                                                                       \
  } while (0)

#define GU_COMPUTE(OCOL, W1, W3) do {                                       \
    float V[32];                                                            \
    _Pragma("unroll") for (int i = 0; i < 32; ++i) V[i] = 0.f;              \
    _Pragma("unroll")                                                       \
    for (int c = 0; c < 4; ++c) {                                           \
      const int idx = c * 64 + lane;                                        \
      const float4 w1v = W1[c], w3v = W3[c];                                \
      _Pragma("unroll")                                                     \
      for (int b = 0; b < 16; ++b) {                                        \
        const float4 xv = ldsf[b * 256 + idx];                              \
        V[2 * b]     += w1v.x * xv.x + w1v.y * xv.y + w1v.z * xv.z + w1v.w * xv.w; \
        V[2 * b + 1] += w3v.x * xv.x + w3v.y * xv.y + w3v.z * xv.z + w3v.w * xv.w; \
      }                                                                     \
    }                                                                       \
    _Pragma("unroll")                                                       \
    for (int s = 0; s < 4; ++s) {                                           \
      const int off = 1 << s, n2 = 16 >> s;                                 \
      _Pragma("unroll")                                                     \
      for (int i = 0; i < n2; ++i) {                                        \
        float lo = V[i], hi = V[i + n2];                                    \
        float send = (lane & off) ? lo : hi;                                \
        float got = __shfl_xor(send, off);                                  \
        V[i] = (lane & off) ? (hi + got) : (lo + got);                      \
      }                                                                     \
    }                                                                       \
    V[0] += __shfl_xor(V[0], 16); V[0] += __shfl_xor(V[0], 32);             \
    V[1] += __shfl_xor(V[1], 16); V[1] += __shfl_xor(V[1], 32);             \
    if (lane < 16) {                                                        \
      const int b = ((lane & 1) << 3) | ((lane & 2) << 1) |                 \
                    ((lane & 4) >> 1) | ((lane & 8) >> 3);                  \
      const float g = V[0] + 0.5f * (ws[T1_OFF + 2 * b] * b1[2 * (OCOL)] +  \
                                     ws[T1_OFF + 2 * b + 1] * b1[2 * (OCOL) + 1]); \
      const float u = V[1] + 0.5f * (ws[T3_OFF + 2 * b] * b3[2 * (OCOL)] +  \
                                     ws[T3_OFF + 2 * b + 1] * b3[2 * (OCOL) + 1]); \
      hvecT[(OCOL) * 16 + b] = (g / (1.f + __expf(-g))) * u;                \
    }                                                                       \
  } while (0)

__global__ __launch_bounds__(512) void k_gateup(const float* __restrict__ w1q,
                                                const float* __restrict__ w3q,
                                                const float* __restrict__ b1,
                                                const float* __restrict__ b3,
                                                const float* __restrict__ ws,
                                                float* __restrict__ hvecT) {
  __shared__ float4 lds4[4096];   // xs f32 [16][1024] = 64 KB
  const int t = threadIdx.x;
  const float4* xs4 = (const float4*)(ws + XS1_OFF);
#pragma unroll
  for (int i = 0; i < 8; ++i) lds4[t + i * 512] = xs4[t + i * 512];

  const int wave = t >> 6, lane = t & 63;
  const float4* ldsf = lds4;
  const int obase = blockIdx.x * 16;
  const int oA = obase + wave;        // cols 0..7 of the block
  const int oB = obase + 8 + wave;    // cols 8..15

  float4 A1[4], A3[4], B1[4], B3[4];
  GU_LOADW(oA, A1, A3);               // 8 loads in flight
  GU_LOADW(oB, B1, B3);               // +8 more
  __syncthreads();                    // xs staged
  GU_COMPUTE(oA, A1, A3);             // waits only on A's loads; B stays in flight
  GU_COMPUTE(oB, B1, B3);
}

// ---------------------------------------------------------------------------
// prep2: hs[b][j] = sum_k hvec[b][k*2752+j] (stored bf16); t2 = hvec·a2^T.
__global__ __launch_bounds__(256) void k_prep2(const float* __restrict__ hvecT,
                                               const float* __restrict__ a2,
                                               float* __restrict__ ws) {
  const int b = blockIdx.x, t = threadIdx.x;
  float s0 = 0.f, s1 = 0.f;
  unsigned short* hsb = (unsigned short*)(ws + HSB_OFF);
  for (int j = t; j < HQ; j += 256) {
    float v0 = hvecT[j * 16 + b];
    float v1 = hvecT[(j + HQ) * 16 + b];
    float v2 = hvecT[(j + 2 * HQ) * 16 + b];
    float v3 = hvecT[(j + 3 * HQ) * 16 + b];
    hsb[b * HQ + j] = f2bf(v0 + v1 + v2 + v3);
    s0 += v0 * a2[j] + v1 * a2[j + HQ] + v2 * a2[j + 2 * HQ] + v3 * a2[j + 3 * HQ];
    s1 += v0 * a2[HID + j] + v1 * a2[HID + j + HQ] +
          v2 * a2[HID + j + 2 * HQ] + v3 * a2[HID + j + 3 * HQ];
  }
  __shared__ float2 rb[256];
  rb[t] = make_float2(s0, s1);
  __syncthreads();
  for (int s = 128; s > 0; s >>= 1) {
    if (t < s) { rb[t].x += rb[t + s].x; rb[t].y += rb[t + s].y; }
    __syncthreads();
  }
  if (t == 0) { ws[T2_OFF + b * 2] = rb[0].x; ws[T2_OFF + b * 2 + 1] = rb[0].y; }
}

// ---------------------------------------------------------------------------
// down: 256 blocks x 1024 thr, 1 col/wave, hs bf16 fully LDS-resident (88 KB).
__global__ __launch_bounds__(1024) void k_down(const float* __restrict__ w2q,
                                               const float* __restrict__ b2,
                                               const float* __restrict__ ws,
                                               float* __restrict__ out) {
  __shared__ uint4 lds4[5504];   // hs bf16 [16][2752] = 88 KB
  const int t = threadIdx.x;
  const uint4* hsb4 = (const uint4*)(ws + HSB_OFF);
  for (int i = t; i < 5504; i += 1024) lds4[i] = hsb4[i];

  const int wave = t >> 6, lane = t & 63;
  const uint2* ldsb = (const uint2*)lds4;     // [b*688 + j], 4 bf16 each
  const int o = blockIdx.x * 16 + wave;
  const float4* wp = (const float4*)w2q + (size_t)o * 688;

  float W[11][4];  // prefetch all 11 weight chunks (44 VGPRs)
#pragma unroll
  for (int cc = 0; cc < 10; ++cc) {
    const float4 wv = wp[cc * 64 + lane];
    W[cc][0] = wv.x; W[cc][1] = wv.y; W[cc][2] = wv.z; W[cc][3] = wv.w;
  }
  {
    const int j = 640 + (lane < 48 ? lane : 0);
    const float4 wv = wp[j];
    W[10][0] = wv.x; W[10][1] = wv.y; W[10][2] = wv.z; W[10][3] = wv.w;
  }
  __syncthreads();

  float V[16];
#pragma unroll
  for (int i = 0; i < 16; ++i) V[i] = 0.f;

#pragma unroll
  for (int cc = 0; cc < 10; ++cc) {
    const int j = cc * 64 + lane;
#pragma unroll
    for (int b = 0; b < 16; ++b) {
      uint2 p = ldsb[b * 688 + j];
      float x0 = __uint_as_float(p.x << 16);
      float x1 = __uint_as_float(p.x & 0xffff0000u);
      float x2 = __uint_as_float(p.y << 16);
      float x3 = __uint_as_float(p.y & 0xffff0000u);
      V[b] += W[cc][0] * x0 + W[cc][1] * x1 + W[cc][2] * x2 + W[cc][3] * x3;
    }
  }
  if (lane < 48) {                      // tail: j = 640..687
    const int j = 640 + lane;
#pragma unroll
    for (int b = 0; b < 16; ++b) {
      uint2 p = ldsb[b * 688 + j];
      float x0 = __uint_as_float(p.x << 16);
      float x1 = __uint_as_float(p.x & 0xffff0000u);
      float x2 = __uint_as_float(p.y << 16);
      float x3 = __uint_as_float(p.y & 0xffff0000u);
      V[b] += W[10][0] * x0 + W[10][1] * x1 + W[10][2] * x2 + W[10][3] * x3;
    }
  }

#pragma unroll
  for (int s = 0; s < 4; ++s) {
    const int off = 1 << s, n2 = 8 >> s;
#pragma unroll
    for (int i = 0; i < n2; ++i) {
      float lo = V[i], hi = V[i + n2];
      float send = (lane & off) ? lo : hi;
      float got = __shfl_xor(send, off);
      V[i] = (lane & off) ? (hi + got) : (lo + got);
    }
  }
  V[0] += __shfl_xor(V[0], 16);
  V[0] += __shfl_xor(V[0], 32);

  if (lane < 16) {
    const int b = ((lane & 1) << 3) | ((lane & 2) << 1) |
                  ((lane & 4) >> 1) | ((lane & 8) >> 3);
    out[b * DMODEL + o] = V[0] + 0.5f * (ws[T2_OFF + 2 * b] * b2[2 * o] +
                                         ws[T2_OFF + 2 * b + 1] * b2[2 * o + 1]);
  }
}

// ---------------------------------------------------------------------------
extern "C" void kernel_launch(void* const* d_in, const int* in_sizes, int n_in,
                              void* d_out, int out_size, void* d_ws, size_t ws_size,
                              hipStream_t stream) {
  const float* x   = (const float*)d_in[0];
  const float* w1q = (const float*)d_in[1];
  const float* a1  = (const float*)d_in[2];
  const float* b1  = (const float*)d_in[3];
  const float* w3q = (const float*)d_in[4];
  const float* a3  = (const float*)d_in[5];
  const float* b3  = (const float*)d_in[6];
  const float* w2q = (const float*)d_in[7];
  const float* a2  = (const float*)d_in[8];
  const float* b2  = (const float*)d_in[9];
  float* out = (float*)d_out;
  float* ws  = (float*)d_ws;
  float* hvecT = ws + HVT_OFF;

  k_prep1<<<16, 256, 0, stream>>>(x, a1, a3, ws);
  k_gateup<<<688, 512, 0, stream>>>(w1q, w3q, b1, b3, ws, hvecT);
  k_prep2<<<16, 256, 0, stream>>>(hvecT, a2, ws);
  k_down<<<256, 1024, 0, stream>>>(w2q, b2, ws, out);
}

// Round 5
// 113.418 us; speedup vs baseline: 3.5644x; 1.7491x over previous
//
#include <hip/hip_runtime.h>
#include <hip/hip_bf16.h>

// QLoRA SwiGLU MLP, B=16 tokens, d=4096, h=11008, r=2.
// tile(wq,(1,4)) => x @ W^T == fold4(x) @ wq^T  (skinny GEMM, K = in/4).
// gateup: xs f32 in 64KB LDS, 512 thr, 2 cols/wave pipelined.
// down:   hs bf16 in 88KB LDS, 512 thr, 2 cols/wave pipelined (R4: was 1024
//         thr -> 64-VGPR clamp -> 293MB scratch spill; 512 thr = 256 VGPR budget).
// LoRA r=2 fused into epilogues. NO min-waves launch bounds.

#define NB     16
#define DMODEL 4096
#define HID    11008
#define DQ     1024   // DMODEL/4
#define HQ     2752   // HID/4

// workspace layout (float offsets)
#define XS1_OFF 0         // xs f32 [16][1024]
#define T1_OFF  16384     // [16][2] f32
#define T3_OFF  16416
#define HVT_OFF 16448     // hvecT f32 [11008][16]
#define HSB_OFF 192576    // hs bf16 [16][2752] = 22016 floats
#define T2_OFF  214592    // [16][2] f32

__device__ __forceinline__ unsigned short f2bf(float f) {
  unsigned u = __float_as_uint(f);
  unsigned r = u + 0x7fffu + ((u >> 16) & 1u);   // RNE
  return (unsigned short)(r >> 16);
}

// ---------------------------------------------------------------------------
// prep1: xs[b][j] = sum_k x[b][k*1024+j] (f32); t1,t3 = LoRA A dots.
__global__ __launch_bounds__(256) void k_prep1(const float* __restrict__ x,
                                               const float* __restrict__ a1,
                                               const float* __restrict__ a3,
                                               float* __restrict__ ws) {
  const int b = blockIdx.x, t = threadIdx.x;
  const float4* x4  = (const float4*)(x) + b * (DMODEL / 4);
  const float4* a14 = (const float4*)a1;
  const float4* a34 = (const float4*)a3;
  float4 xs = make_float4(0.f, 0.f, 0.f, 0.f);
  float s10 = 0.f, s11 = 0.f, s30 = 0.f, s31 = 0.f;
#pragma unroll
  for (int k = 0; k < 4; ++k) {
    float4 xv  = x4[k * 256 + t];
    xs.x += xv.x; xs.y += xv.y; xs.z += xv.z; xs.w += xv.w;
    float4 a10 = a14[k * 256 + t];
    float4 a11 = a14[1024 + k * 256 + t];
    float4 a30 = a34[k * 256 + t];
    float4 a31 = a34[1024 + k * 256 + t];
    s10 += xv.x * a10.x + xv.y * a10.y + xv.z * a10.z + xv.w * a10.w;
    s11 += xv.x * a11.x + xv.y * a11.y + xv.z * a11.z + xv.w * a11.w;
    s30 += xv.x * a30.x + xv.y * a30.y + xv.z * a30.z + xv.w * a30.w;
    s31 += xv.x * a31.x + xv.y * a31.y + xv.z * a31.z + xv.w * a31.w;
  }
  ((float4*)(ws + XS1_OFF))[b * 256 + t] = xs;

  __shared__ float4 rb[256];
  rb[t] = make_float4(s10, s11, s30, s31);
  __syncthreads();
  for (int s = 128; s > 0; s >>= 1) {
    if (t < s) {
      rb[t].x += rb[t + s].x; rb[t].y += rb[t + s].y;
      rb[t].z += rb[t + s].z; rb[t].w += rb[t + s].w;
    }
    __syncthreads();
  }
  if (t == 0) {
    ws[T1_OFF + b * 2]     = rb[0].x;
    ws[T1_OFF + b * 2 + 1] = rb[0].y;
    ws[T3_OFF + b * 2]     = rb[0].z;
    ws[T3_OFF + b * 2 + 1] = rb[0].w;
  }
}

// ---------------------------------------------------------------------------
// gateup: 688 blocks x 512 thr; 16 cols/block; 2 cols/wave, both cols' weight
// loads issued before first compute (counted-vmcnt overlap). xs f32 64KB LDS.
#define GU_LOADW(OCOL, W1, W3) do {                                         \
    const float4* _p1 = (const float4*)w1q + (size_t)(OCOL) * 256;          \
    const float4* _p3 = (const float4*)w3q + (size_t)(OCOL) * 256;          \
    _Pragma("unroll")                                                       \
    for (int c = 0; c < 4; ++c) {                                           \
      W1[c] = _p1[c * 64 + lane];                                           \
      W3[c] = _p3[c * 64 + lane];                                           \
    }                                                                       \
  } while (0)

#define GU_COMPUTE(OCOL, W1, W3) do {                                       \
    float V[32];                                                            \
    _Pragma("unroll") for (int i = 0; i < 32; ++i) V[i] = 0.f;              \
    _Pragma("unroll")                                                       \
    for (int c = 0; c < 4; ++c) {                                           \
      const int idx = c * 64 + lane;                                        \
      const float4 w1v = W1[c], w3v = W3[c];                                \
      _Pragma("unroll")                                                     \
      for (int b = 0; b < 16; ++b) {                                        \
        const float4 xv = ldsf[b * 256 + idx];                              \
        V[2 * b]     += w1v.x * xv.x + w1v.y * xv.y + w1v.z * xv.z + w1v.w * xv.w; \
        V[2 * b + 1] += w3v.x * xv.x + w3v.y * xv.y + w3v.z * xv.z + w3v.w * xv.w; \
      }                                                                     \
    }                                                                       \
    _Pragma("unroll")                                                       \
    for (int s = 0; s < 4; ++s) {                                           \
      const int off = 1 << s, n2 = 16 >> s;                                 \
      _Pragma("unroll")                                                     \
      for (int i = 0; i < n2; ++i) {                                        \
        float lo = V[i], hi = V[i + n2];                                    \
        float send = (lane & off) ? lo : hi;                                \
        float got = __shfl_xor(send, off);                                  \
        V[i] = (lane & off) ? (hi + got) : (lo + got);                      \
      }                                                                     \
    }                                                                       \
    V[0] += __shfl_xor(V[0], 16); V[0] += __shfl_xor(V[0], 32);             \
    V[1] += __shfl_xor(V[1], 16); V[1] += __shfl_xor(V[1], 32);             \
    if (lane < 16) {                                                        \
      const int b = ((lane & 1) << 3) | ((lane & 2) << 1) |                 \
                    ((lane & 4) >> 1) | ((lane & 8) >> 3);                  \
      const float g = V[0] + 0.5f * (ws[T1_OFF + 2 * b] * b1[2 * (OCOL)] +  \
                                     ws[T1_OFF + 2 * b + 1] * b1[2 * (OCOL) + 1]); \
      const float u = V[1] + 0.5f * (ws[T3_OFF + 2 * b] * b3[2 * (OCOL)] +  \
                                     ws[T3_OFF + 2 * b + 1] * b3[2 * (OCOL) + 1]); \
      hvecT[(OCOL) * 16 + b] = (g / (1.f + __expf(-g))) * u;                \
    }                                                                       \
  } while (0)

__global__ __launch_bounds__(512) void k_gateup(const float* __restrict__ w1q,
                                                const float* __restrict__ w3q,
                                                const float* __restrict__ b1,
                                                const float* __restrict__ b3,
                                                const float* __restrict__ ws,
                                                float* __restrict__ hvecT) {
  __shared__ float4 lds4[4096];   // xs f32 [16][1024] = 64 KB
  const int t = threadIdx.x;
  const float4* xs4 = (const float4*)(ws + XS1_OFF);
#pragma unroll
  for (int i = 0; i < 8; ++i) lds4[t + i * 512] = xs4[t + i * 512];

  const int wave = t >> 6, lane = t & 63;
  const float4* ldsf = lds4;
  const int obase = blockIdx.x * 16;
  const int oA = obase + wave;        // cols 0..7 of the block
  const int oB = obase + 8 + wave;    // cols 8..15

  float4 A1[4], A3[4], B1[4], B3[4];
  GU_LOADW(oA, A1, A3);               // 8 loads in flight
  GU_LOADW(oB, B1, B3);               // +8 more
  __syncthreads();                    // xs staged
  GU_COMPUTE(oA, A1, A3);             // waits only on A's loads; B stays in flight
  GU_COMPUTE(oB, B1, B3);
}

// ---------------------------------------------------------------------------
// prep2: hs[b][j] = sum_k hvec[b][k*2752+j] (stored bf16); t2 = hvec·a2^T.
__global__ __launch_bounds__(256) void k_prep2(const float* __restrict__ hvecT,
                                               const float* __restrict__ a2,
                                               float* __restrict__ ws) {
  const int b = blockIdx.x, t = threadIdx.x;
  float s0 = 0.f, s1 = 0.f;
  unsigned short* hsb = (unsigned short*)(ws + HSB_OFF);
  for (int j = t; j < HQ; j += 256) {
    float v0 = hvecT[j * 16 + b];
    float v1 = hvecT[(j + HQ) * 16 + b];
    float v2 = hvecT[(j + 2 * HQ) * 16 + b];
    float v3 = hvecT[(j + 3 * HQ) * 16 + b];
    hsb[b * HQ + j] = f2bf(v0 + v1 + v2 + v3);
    s0 += v0 * a2[j] + v1 * a2[j + HQ] + v2 * a2[j + 2 * HQ] + v3 * a2[j + 3 * HQ];
    s1 += v0 * a2[HID + j] + v1 * a2[HID + j + HQ] +
          v2 * a2[HID + j + 2 * HQ] + v3 * a2[HID + j + 3 * HQ];
  }
  __shared__ float2 rb[256];
  rb[t] = make_float2(s0, s1);
  __syncthreads();
  for (int s = 128; s > 0; s >>= 1) {
    if (t < s) { rb[t].x += rb[t + s].x; rb[t].y += rb[t + s].y; }
    __syncthreads();
  }
  if (t == 0) { ws[T2_OFF + b * 2] = rb[0].x; ws[T2_OFF + b * 2 + 1] = rb[0].y; }
}

// ---------------------------------------------------------------------------
// down: 256 blocks x 512 thr; 16 cols/block; 2 cols/wave, both cols' 11 weight
// chunks prefetched before the staging barrier. hs bf16 in 88KB LDS.
#define DN_LOADW(OCOL, W) do {                                              \
    const float4* _wp = (const float4*)w2q + (size_t)(OCOL) * 688;          \
    _Pragma("unroll")                                                       \
    for (int cc = 0; cc < 10; ++cc) {                                       \
      const float4 wv = _wp[cc * 64 + lane];                                \
      W[cc][0] = wv.x; W[cc][1] = wv.y; W[cc][2] = wv.z; W[cc][3] = wv.w;   \
    }                                                                       \
    {                                                                       \
      const float4 wv = _wp[640 + (lane < 48 ? lane : 0)];                  \
      W[10][0] = wv.x; W[10][1] = wv.y; W[10][2] = wv.z; W[10][3] = wv.w;   \
    }                                                                       \
  } while (0)

#define DN_COMPUTE(OCOL, W) do {                                            \
    float V[16];                                                            \
    _Pragma("unroll") for (int i = 0; i < 16; ++i) V[i] = 0.f;              \
    _Pragma("unroll")                                                       \
    for (int cc = 0; cc < 10; ++cc) {                                       \
      const int j = cc * 64 + lane;                                         \
      _Pragma("unroll")                                                     \
      for (int b = 0; b < 16; ++b) {                                        \
        uint2 p = ldsb[b * 688 + j];                                        \
        float x0 = __uint_as_float(p.x << 16);                              \
        float x1 = __uint_as_float(p.x & 0xffff0000u);                      \
        float x2 = __uint_as_float(p.y << 16);                              \
        float x3 = __uint_as_float(p.y & 0xffff0000u);                      \
        V[b] += W[cc][0] * x0 + W[cc][1] * x1 + W[cc][2] * x2 + W[cc][3] * x3; \
      }                                                                     \
    }                                                                       \
    if (lane < 48) {                                                        \
      const int j = 640 + lane;                                             \
      _Pragma("unroll")                                                     \
      for (int b = 0; b < 16; ++b) {                                        \
        uint2 p = ldsb[b * 688 + j];                                        \
        float x0 = __uint_as_float(p.x << 16);                              \
        float x1 = __uint_as_float(p.x & 0xffff0000u);                      \
        float x2 = __uint_as_float(p.y << 16);                              \
        float x3 = __uint_as_float(p.y & 0xffff0000u);                      \
        V[b] += W[10][0] * x0 + W[10][1] * x1 + W[10][2] * x2 + W[10][3] * x3; \
      }                                                                     \
    }                                                                       \
    _Pragma("unroll")                                                       \
    for (int s = 0; s < 4; ++s) {                                           \
      const int off = 1 << s, n2 = 8 >> s;                                  \
      _Pragma("unroll")                                                     \
      for (int i = 0; i < n2; ++i) {                                        \
        float lo = V[i], hi = V[i + n2];                                    \
        float send = (lane & off) ? lo : hi;                                \
        float got = __shfl_xor(send, off);                                  \
        V[i] = (lane & off) ? (hi + got) : (lo + got);                      \
      }                                                                     \
    }                                                                       \
    V[0] += __shfl_xor(V[0], 16);                                           \
    V[0] += __shfl_xor(V[0], 32);                                           \
    if (lane < 16) {                                                        \
      const int b = ((lane & 1) << 3) | ((lane & 2) << 1) |                 \
                    ((lane & 4) >> 1) | ((lane & 8) >> 3);                  \
      out[b * DMODEL + (OCOL)] = V[0] +                                     \
          0.5f * (ws[T2_OFF + 2 * b] * b2[2 * (OCOL)] +                     \
                  ws[T2_OFF + 2 * b + 1] * b2[2 * (OCOL) + 1]);             \
    }                                                                       \
  } while (0)

__global__ __launch_bounds__(512) void k_down(const float* __restrict__ w2q,
                                              const float* __restrict__ b2,
                                              const float* __restrict__ ws,
                                              float* __restrict__ out) {
  __shared__ uint4 lds4[5504];   // hs bf16 [16][2752] = 88 KB
  const int t = threadIdx.x;
  const uint4* hsb4 = (const uint4*)(ws + HSB_OFF);
#pragma unroll
  for (int i = 0; i < 10; ++i) lds4[t + i * 512] = hsb4[t + i * 512];
  if (t < 384) lds4[5120 + t] = hsb4[5120 + t];

  const int wave = t >> 6, lane = t & 63;
  const uint2* ldsb = (const uint2*)lds4;     // [b*688 + j], 4 bf16 each
  const int oA = blockIdx.x * 16 + wave;
  const int oB = oA + 8;

  float WA[11][4], WB[11][4];   // 88 VGPRs of weights, all in flight
  DN_LOADW(oA, WA);
  DN_LOADW(oB, WB);
  __syncthreads();              // hs staged
  DN_COMPUTE(oA, WA);           // waits on A's loads; B's stay in flight
  DN_COMPUTE(oB, WB);
}

// ---------------------------------------------------------------------------
extern "C" void kernel_launch(void* const* d_in, const int* in_sizes, int n_in,
                              void* d_out, int out_size, void* d_ws, size_t ws_size,
                              hipStream_t stream) {
  const float* x   = (const float*)d_in[0];
  const float* w1q = (const float*)d_in[1];
  const float* a1  = (const float*)d_in[2];
  const float* b1  = (const float*)d_in[3];
  const float* w3q = (const float*)d_in[4];
  const float* a3  = (const float*)d_in[5];
  const float* b3  = (const float*)d_in[6];
  const float* w2q = (const float*)d_in[7];
  const float* a2  = (const float*)d_in[8];
  const float* b2  = (const float*)d_in[9];
  float* out = (float*)d_out;
  float* ws  = (float*)d_ws;
  float* hvecT = ws + HVT_OFF;

  k_prep1<<<16, 256, 0, stream>>>(x, a1, a3, ws);
  k_gateup<<<688, 512, 0, stream>>>(w1q, w3q, b1, b3, ws, hvecT);
  k_prep2<<<16, 256, 0, stream>>>(hvecT, a2, ws);
  k_down<<<256, 512, 0, stream>>>(w2q, b2, ws, out);
}

// Round 6
// 76.600 us; speedup vs baseline: 5.2776x; 1.4806x over previous
//
#include <hip/hip_runtime.h>
#include <hip/hip_bf16.h>

// QLoRA SwiGLU MLP, B=16 tokens, d=4096, h=11008, r=2.
// tile(wq,(1,4)) => x @ W^T == fold4(x) @ wq^T  (skinny GEMM, K = in/4).
// Persistent blocks: 256 blocks x 512 thr; stage activations in LDS ONCE,
// then grid-stride over output columns with alternating load/compute so
// weight loads stay in flight. VGPR discipline (512-thr cap = 128): never
// let staging regs (44) and BOTH weight buffers (88) be live together —
// that was R5's k_down spill (132 MB scratch writes, 780 GB/s).

#define NB     16
#define DMODEL 4096
#define HID    11008
#define DQ     1024   // DMODEL/4
#define HQ     2752   // HID/4

// workspace layout (float offsets)
#define XS1_OFF 0         // xs f32 [16][1024]
#define T1_OFF  16384     // [16][2] f32
#define T3_OFF  16416
#define HVT_OFF 16448     // hvecT f32 [11008][16]
#define HSB_OFF 192576    // hs bf16 [16][2752] = 22016 floats
#define T2_OFF  214592    // [16][2] f32

__device__ __forceinline__ unsigned short f2bf(float f) {
  unsigned u = __float_as_uint(f);
  unsigned r = u + 0x7fffu + ((u >> 16) & 1u);   // RNE
  return (unsigned short)(r >> 16);
}

// ---------------------------------------------------------------------------
// prep1: xs[b][j] = sum_k x[b][k*1024+j] (f32); t1,t3 = LoRA A dots.
__global__ __launch_bounds__(256) void k_prep1(const float* __restrict__ x,
                                               const float* __restrict__ a1,
                                               const float* __restrict__ a3,
                                               float* __restrict__ ws) {
  const int b = blockIdx.x, t = threadIdx.x;
  const float4* x4  = (const float4*)(x) + b * (DMODEL / 4);
  const float4* a14 = (const float4*)a1;
  const float4* a34 = (const float4*)a3;
  float4 xs = make_float4(0.f, 0.f, 0.f, 0.f);
  float s10 = 0.f, s11 = 0.f, s30 = 0.f, s31 = 0.f;
#pragma unroll
  for (int k = 0; k < 4; ++k) {
    float4 xv  = x4[k * 256 + t];
    xs.x += xv.x; xs.y += xv.y; xs.z += xv.z; xs.w += xv.w;
    float4 a10 = a14[k * 256 + t];
    float4 a11 = a14[1024 + k * 256 + t];
    float4 a30 = a34[k * 256 + t];
    float4 a31 = a34[1024 + k * 256 + t];
    s10 += xv.x * a10.x + xv.y * a10.y + xv.z * a10.z + xv.w * a10.w;
    s11 += xv.x * a11.x + xv.y * a11.y + xv.z * a11.z + xv.w * a11.w;
    s30 += xv.x * a30.x + xv.y * a30.y + xv.z * a30.z + xv.w * a30.w;
    s31 += xv.x * a31.x + xv.y * a31.y + xv.z * a31.z + xv.w * a31.w;
  }
  ((float4*)(ws + XS1_OFF))[b * 256 + t] = xs;

  __shared__ float4 rb[256];
  rb[t] = make_float4(s10, s11, s30, s31);
  __syncthreads();
  for (int s = 128; s > 0; s >>= 1) {
    if (t < s) {
      rb[t].x += rb[t + s].x; rb[t].y += rb[t + s].y;
      rb[t].z += rb[t + s].z; rb[t].w += rb[t + s].w;
    }
    __syncthreads();
  }
  if (t == 0) {
    ws[T1_OFF + b * 2]     = rb[0].x;
    ws[T1_OFF + b * 2 + 1] = rb[0].y;
    ws[T3_OFF + b * 2]     = rb[0].z;
    ws[T3_OFF + b * 2 + 1] = rb[0].w;
  }
}

// ---------------------------------------------------------------------------
// gateup: 256 blocks x 512 thr (8 waves). xs f32 staged once in 64KB LDS.
// Cols: o = it*2048 + blockIdx.x*8 + wave, it = 0..5 (it<5 always valid).
// Alternating A/B weight buffers: load(next) issued before compute(cur).
#define GU_LOADW(OCOL, W1, W3) do {                                         \
    const float4* _p1 = (const float4*)w1q + (size_t)(OCOL) * 256;          \
    const float4* _p3 = (const float4*)w3q + (size_t)(OCOL) * 256;          \
    _Pragma("unroll")                                                       \
    for (int c = 0; c < 4; ++c) {                                           \
      W1[c] = _p1[c * 64 + lane];                                           \
      W3[c] = _p3[c * 64 + lane];                                           \
    }                                                                       \
  } while (0)

#define GU_COMPUTE(OCOL, W1, W3) do {                                       \
    float V[32];                                                            \
    _Pragma("unroll") for (int i = 0; i < 32; ++i) V[i] = 0.f;              \
    _Pragma("unroll")                                                       \
    for (int c = 0; c < 4; ++c) {                                           \
      const int idx = c * 64 + lane;                                        \
      const float4 w1v = W1[c], w3v = W3[c];                                \
      _Pragma("unroll")                                                     \
      for (int b = 0; b < 16; ++b) {                                        \
        const float4 xv = ldsf[b * 256 + idx];                              \
        V[2 * b]     += w1v.x * xv.x + w1v.y * xv.y + w1v.z * xv.z + w1v.w * xv.w; \
        V[2 * b + 1] += w3v.x * xv.x + w3v.y * xv.y + w3v.z * xv.z + w3v.w * xv.w; \
      }                                                                     \
    }                                                                       \
    _Pragma("unroll")                                                       \
    for (int s = 0; s < 4; ++s) {                                           \
      const int off = 1 << s, n2 = 16 >> s;                                 \
      _Pragma("unroll")                                                     \
      for (int i = 0; i < n2; ++i) {                                        \
        float lo = V[i], hi = V[i + n2];                                    \
        float send = (lane & off) ? lo : hi;                                \
        float got = __shfl_xor(send, off);                                  \
        V[i] = (lane & off) ? (hi + got) : (lo + got);                      \
      }                                                                     \
    }                                                                       \
    V[0] += __shfl_xor(V[0], 16); V[0] += __shfl_xor(V[0], 32);             \
    V[1] += __shfl_xor(V[1], 16); V[1] += __shfl_xor(V[1], 32);             \
    if (lane < 16) {                                                        \
      const int b = ((lane & 1) << 3) | ((lane & 2) << 1) |                 \
                    ((lane & 4) >> 1) | ((lane & 8) >> 3);                  \
      const float g = V[0] + 0.5f * (ws[T1_OFF + 2 * b] * b1[2 * (OCOL)] +  \
                                     ws[T1_OFF + 2 * b + 1] * b1[2 * (OCOL) + 1]); \
      const float u = V[1] + 0.5f * (ws[T3_OFF + 2 * b] * b3[2 * (OCOL)] +  \
                                     ws[T3_OFF + 2 * b + 1] * b3[2 * (OCOL) + 1]); \
      hvecT[(OCOL) * 16 + b] = (g / (1.f + __expf(-g))) * u;                \
    }                                                                       \
  } while (0)

__global__ __launch_bounds__(512) void k_gateup(const float* __restrict__ w1q,
                                                const float* __restrict__ w3q,
                                                const float* __restrict__ b1,
                                                const float* __restrict__ b3,
                                                const float* __restrict__ ws,
                                                float* __restrict__ hvecT) {
  __shared__ float4 lds4[4096];   // xs f32 [16][1024] = 64 KB
  const int t = threadIdx.x;
  const int wave = t >> 6, lane = t & 63;
  const int base = blockIdx.x * 8 + wave;       // 0..2047

  float4 A1[4], A3[4], B1[4], B3[4];
  GU_LOADW(base, A1, A3);          // iter-0 weights in flight during staging

  const float4* xs4 = (const float4*)(ws + XS1_OFF);
#pragma unroll
  for (int i = 0; i < 8; ++i) lds4[t + i * 512] = xs4[t + i * 512];
  __syncthreads();

  const float4* ldsf = lds4;
  GU_LOADW(base + 2048, B1, B3);
  GU_COMPUTE(base, A1, A3);
  GU_LOADW(base + 4096, A1, A3);
  GU_COMPUTE(base + 2048, B1, B3);
  GU_LOADW(base + 6144, B1, B3);
  GU_COMPUTE(base + 4096, A1, A3);
  GU_LOADW(base + 8192, A1, A3);
  GU_COMPUTE(base + 6144, B1, B3);
  const int o5 = base + 10240;                  // valid iff base < 768
  const bool v5 = (o5 < HID);
  GU_LOADW(v5 ? o5 : base, B1, B3);
  GU_COMPUTE(base + 8192, A1, A3);              // max 10239 < 11008, always valid
  if (v5) GU_COMPUTE(o5, B1, B3);
}

// ---------------------------------------------------------------------------
// prep2: hs[b][j] = sum_k hvec[b][k*2752+j] (stored bf16); t2 = hvec·a2^T.
__global__ __launch_bounds__(256) void k_prep2(const float* __restrict__ hvecT,
                                               const float* __restrict__ a2,
                                               float* __restrict__ ws) {
  const int b = blockIdx.x, t = threadIdx.x;
  float s0 = 0.f, s1 = 0.f;
  unsigned short* hsb = (unsigned short*)(ws + HSB_OFF);
  for (int j = t; j < HQ; j += 256) {
    float v0 = hvecT[j * 16 + b];
    float v1 = hvecT[(j + HQ) * 16 + b];
    float v2 = hvecT[(j + 2 * HQ) * 16 + b];
    float v3 = hvecT[(j + 3 * HQ) * 16 + b];
    hsb[b * HQ + j] = f2bf(v0 + v1 + v2 + v3);
    s0 += v0 * a2[j] + v1 * a2[j + HQ] + v2 * a2[j + 2 * HQ] + v3 * a2[j + 3 * HQ];
    s1 += v0 * a2[HID + j] + v1 * a2[HID + j + HQ] +
          v2 * a2[HID + j + 2 * HQ] + v3 * a2[HID + j + 3 * HQ];
  }
  __shared__ float2 rb[256];
  rb[t] = make_float2(s0, s1);
  __syncthreads();
  for (int s = 128; s > 0; s >>= 1) {
    if (t < s) { rb[t].x += rb[t + s].x; rb[t].y += rb[t + s].y; }
    __syncthreads();
  }
  if (t == 0) { ws[T2_OFF + b * 2] = rb[0].x; ws[T2_OFF + b * 2 + 1] = rb[0].y; }
}

// ---------------------------------------------------------------------------
// down: 256 blocks x 512 thr (8 waves). hs bf16 staged once in 88KB LDS.
// Cols: cA = blockIdx*8+wave, cB = cA+2048 (exactly covers 4096).
// VGPR discipline: only WA (44) overlaps staging; WB loads after the barrier.
#define DN_LOADW(OCOL, W) do {                                              \
    const float4* _wp = (const float4*)w2q + (size_t)(OCOL) * 688;          \
    _Pragma("unroll")                                                       \
    for (int cc = 0; cc < 10; ++cc) {                                       \
      const float4 wv = _wp[cc * 64 + lane];                                \
      W[cc][0] = wv.x; W[cc][1] = wv.y; W[cc][2] = wv.z; W[cc][3] = wv.w;   \
    }                                                                       \
    {                                                                       \
      const float4 wv = _wp[640 + (lane < 48 ? lane : 0)];                  \
      W[10][0] = wv.x; W[10][1] = wv.y; W[10][2] = wv.z; W[10][3] = wv.w;   \
    }                                                                       \
  } while (0)

#define DN_COMPUTE(OCOL, W) do {                                            \
    float V[16];                                                            \
    _Pragma("unroll") for (int i = 0; i < 16; ++i) V[i] = 0.f;              \
    _Pragma("unroll")                                                       \
    for (int cc = 0; cc < 10; ++cc) {                                       \
      const int j = cc * 64 + lane;                                         \
      _Pragma("unroll")                                                     \
      for (int b = 0; b < 16; ++b) {                                        \
        uint2 p = ldsb[b * 688 + j];                                        \
        float x0 = __uint_as_float(p.x << 16);                              \
        float x1 = __uint_as_float(p.x & 0xffff0000u);                      \
        float x2 = __uint_as_float(p.y << 16);                              \
        float x3 = __uint_as_float(p.y & 0xffff0000u);                      \
        V[b] += W[cc][0] * x0 + W[cc][1] * x1 + W[cc][2] * x2 + W[cc][3] * x3; \
      }                                                                     \
    }                                                                       \
    if (lane < 48) {                                                        \
      const int j = 640 + lane;                                             \
      _Pragma("unroll")                                                     \
      for (int b = 0; b < 16; ++b) {                                        \
        uint2 p = ldsb[b * 688 + j];                                        \
        float x0 = __uint_as_float(p.x << 16);                              \
        float x1 = __uint_as_float(p.x & 0xffff0000u);                      \
        float x2 = __uint_as_float(p.y << 16);                              \
        float x3 = __uint_as_float(p.y & 0xffff0000u);                      \
        V[b] += W[10][0] * x0 + W[10][1] * x1 + W[10][2] * x2 + W[10][3] * x3; \
      }                                                                     \
    }                                                                       \
    _Pragma("unroll")                                                       \
    for (int s = 0; s < 4; ++s) {                                           \
      const int off = 1 << s, n2 = 8 >> s;                                  \
      _Pragma("unroll")                                                     \
      for (int i = 0; i < n2; ++i) {                                        \
        float lo = V[i], hi = V[i + n2];                                    \
        float send = (lane & off) ? lo : hi;                                \
        float got = __shfl_xor(send, off);                                  \
        V[i] = (lane & off) ? (hi + got) : (lo + got);                      \
      }                                                                     \
    }                                                                       \
    V[0] += __shfl_xor(V[0], 16);                                           \
    V[0] += __shfl_xor(V[0], 32);                                           \
    if (lane < 16) {                                                        \
      const int b = ((lane & 1) << 3) | ((lane & 2) << 1) |                 \
                    ((lane & 4) >> 1) | ((lane & 8) >> 3);                  \
      out[b * DMODEL + (OCOL)] = V[0] +                                     \
          0.5f * (ws[T2_OFF + 2 * b] * b2[2 * (OCOL)] +                     \
                  ws[T2_OFF + 2 * b + 1] * b2[2 * (OCOL) + 1]);             \
    }                                                                       \
  } while (0)

__global__ __launch_bounds__(512) void k_down(const float* __restrict__ w2q,
                                              const float* __restrict__ b2,
                                              const float* __restrict__ ws,
                                              float* __restrict__ out) {
  __shared__ uint4 lds4[5504];   // hs bf16 [16][2752] = 88 KB
  const int t = threadIdx.x;
  const int wave = t >> 6, lane = t & 63;
  const int cA = blockIdx.x * 8 + wave;        // 0..2047
  const int cB = cA + 2048;                    // 2048..4095

  float WA[11][4], WB[11][4];
  DN_LOADW(cA, WA);              // in flight during staging (peak ~100 VGPR)

  const uint4* hsb4 = (const uint4*)(ws + HSB_OFF);
#pragma unroll
  for (int i = 0; i < 10; ++i) lds4[t + i * 512] = hsb4[t + i * 512];
  if (t < 384) lds4[5120 + t] = hsb4[5120 + t];
  __syncthreads();

  const uint2* ldsb = (const uint2*)lds4;      // [b*688 + j], 4 bf16 each
  DN_LOADW(cB, WB);              // issued before compute; stays in flight
  DN_COMPUTE(cA, WA);
  DN_COMPUTE(cB, WB);
}

// ---------------------------------------------------------------------------
extern "C" void kernel_launch(void* const* d_in, const int* in_sizes, int n_in,
                              void* d_out, int out_size, void* d_ws, size_t ws_size,
                              hipStream_t stream) {
  const float* x   = (const float*)d_in[0];
  const float* w1q = (const float*)d_in[1];
  const float* a1  = (const float*)d_in[2];
  const float* b1  = (const float*)d_in[3];
  const float* w3q = (const float*)d_in[4];
  const float* a3  = (const float*)d_in[5];
  const float* b3  = (const float*)d_in[6];
  const float* w2q = (const float*)d_in[7];
  const float* a2  = (const float*)d_in[8];
  const float* b2  = (const float*)d_in[9];
  float* out = (float*)d_out;
  float* ws  = (float*)d_ws;
  float* hvecT = ws + HVT_OFF;

  k_prep1<<<16, 256, 0, stream>>>(x, a1, a3, ws);
  k_gateup<<<256, 512, 0, stream>>>(w1q, w3q, b1, b3, ws, hvecT);
  k_prep2<<<16, 256, 0, stream>>>(hvecT, a2, ws);
  k_down<<<256, 512, 0, stream>>>(w2q, b2, ws, out);
}